// Round 1
// baseline (538.401 us; speedup 1.0000x reference)
//
#include <hip/hip_runtime.h>

// QuantLinearBase: out = fakequant_i8(x) @ dequant_i4(W).T + bias
// Strategy: exact integer GEMM on the i8 MFMA pipe.
//   out[m,n] = (s * ws) * sum_k qx[m,k]*qw[n,k] + bias[n]
// where qx = round(x/s) in [-127,127] (int8), qw in [-8,7] (int8), s = amax/127.
// int32 accumulation is exact -> only epilogue fp32 rounding error.

#define BM 128
#define BN 128
#define BK 64

typedef __attribute__((ext_vector_type(4))) int int32x4;

__device__ __forceinline__ void async_copy16(const void* gsrc, void* ldsdst) {
  __builtin_amdgcn_global_load_lds(
      (const __attribute__((address_space(1))) void*)gsrc,
      (__attribute__((address_space(3))) void*)ldsdst, 16, 0, 0);
}

// ---------------- Pass 1: global amax(|x|) ----------------
__global__ void amax_kernel(const float* __restrict__ x,
                            unsigned* __restrict__ amax, int n4) {
  int tid = blockIdx.x * blockDim.x + threadIdx.x;
  int stride = gridDim.x * blockDim.x;
  float m = 0.0f;
  const float4* x4 = (const float4*)x;
  for (int i = tid; i < n4; i += stride) {
    float4 v = x4[i];
    m = fmaxf(m, fmaxf(fmaxf(fabsf(v.x), fabsf(v.y)),
                       fmaxf(fabsf(v.z), fabsf(v.w))));
  }
#pragma unroll
  for (int off = 32; off > 0; off >>= 1)
    m = fmaxf(m, __shfl_down(m, off, 64));
  // |x| >= 0 so float bits compare correctly as unsigned ints
  if ((threadIdx.x & 63) == 0) atomicMax(amax, __float_as_uint(m));
}

// ---------------- Pass 2: quantize x -> int8 ----------------
__global__ void quant_kernel(const float* __restrict__ x,
                             const unsigned* __restrict__ amax_bits,
                             unsigned* __restrict__ qx, int n4) {
  float amax = __uint_as_float(*amax_bits);
  float s = amax / 127.0f;  // exact same op as reference
  if (s == 0.0f) s = 1.0f;
  int tid = blockIdx.x * blockDim.x + threadIdx.x;
  int stride = gridDim.x * blockDim.x;
  const float4* x4 = (const float4*)x;
  for (int i = tid; i < n4; i += stride) {
    float4 v = x4[i];
    int a = __float2int_rn(v.x / s);  // RNE, matches jnp.round
    int b = __float2int_rn(v.y / s);
    int c = __float2int_rn(v.z / s);
    int d = __float2int_rn(v.w / s);
    qx[i] = (unsigned)(a & 0xFF) | ((unsigned)(b & 0xFF) << 8) |
            ((unsigned)(c & 0xFF) << 16) | ((unsigned)(d & 0xFF) << 24);
  }
}

// ---------------- Pass 3: unpack int4 weights -> int8 [O,I] ----------------
__device__ __forceinline__ unsigned pack2(int q) {
  // byte0 (even col) = high nibble - 8, byte1 (odd col) = low nibble - 8
  unsigned hi = (unsigned)((((q >> 4) & 15) - 8) & 0xFF);
  unsigned lo = (unsigned)(((q & 15) - 8) & 0xFF);
  return hi | (lo << 8);
}

__global__ void repack_kernel(const int* __restrict__ qw,
                              uint2* __restrict__ w8, int n4) {
  int tid = blockIdx.x * blockDim.x + threadIdx.x;
  int stride = gridDim.x * blockDim.x;
  const int4* q4 = (const int4*)qw;
  for (int i = tid; i < n4; i += stride) {
    int4 q = q4[i];
    uint2 r;
    r.x = pack2(q.x) | (pack2(q.y) << 16);
    r.y = pack2(q.z) | (pack2(q.w) << 16);
    w8[i] = r;
  }
}

// ---------------- Pass 4: i8 MFMA GEMM, C = A(i8)[M,K] @ Bt(i8)[N,K]^T ------
// m97 structure: 128x128 block tile, 4 waves in 2x2, each wave 4x4 of 16x16
// MFMA tiles, BK=64 (one mfma_i32_16x16x64_i8 consumes the full K-slab),
// global_load_lds width=16 staging (lane order == LDS linear order).
__global__ __launch_bounds__(256) void gemm_i8(
    const char* __restrict__ A, const char* __restrict__ Bt,
    const float* __restrict__ bias, const unsigned* __restrict__ amax_bits,
    const float* __restrict__ wscale, float* __restrict__ C,
    int M, int N, int K) {
  __shared__ char As[BM * BK];
  __shared__ char Bs[BN * BK];

  const int t = threadIdx.x;
  const int wave = t >> 6;
  const int lane = t & 63;
  const int wrow = wave >> 1;   // 2x2 wave grid, 64x64 per wave
  const int wcol = wave & 1;
  const int quad = lane >> 4;
  const int l16 = lane & 15;
  const int bM = blockIdx.x * BM;
  const int bN = blockIdx.y * BN;

  // staging: thread t loads row t>>2 (0..63), byte col (t&3)*16; two issues
  // cover rows 0..63 and 64..127. LDS dst = linear*16 -> row-major [128][64],
  // and per-wave it is base + lane*16 (wave-uniform-base constraint holds).
  const char* aptr = A + (size_t)(bM + (t >> 2)) * K + (t & 3) * 16;
  const char* bptr = Bt + (size_t)(bN + (t >> 2)) * K + (t & 3) * 16;
  char* adst0 = &As[t * 16];
  char* adst1 = &As[4096 + t * 16];
  char* bdst0 = &Bs[t * 16];
  char* bdst1 = &Bs[4096 + t * 16];
  const size_t rowskip = (size_t)64 * K;

  int32x4 acc[4][4] = {};

  for (int k0 = 0; k0 < K; k0 += BK) {
    __syncthreads();  // prior iteration's LDS reads complete
    async_copy16(aptr, adst0);
    async_copy16(aptr + rowskip, adst1);
    async_copy16(bptr, bdst0);
    async_copy16(bptr + rowskip, bdst1);
    aptr += BK;
    bptr += BK;
    __syncthreads();  // vmcnt(0) drain: staging visible

    int32x4 af[4], bf[4];
#pragma unroll
    for (int i = 0; i < 4; ++i)
      af[i] = *(const int32x4*)&As[(wrow * 64 + i * 16 + l16) * BK + quad * 16];
#pragma unroll
    for (int j = 0; j < 4; ++j)
      bf[j] = *(const int32x4*)&Bs[(wcol * 64 + j * 16 + l16) * BK + quad * 16];
#pragma unroll
    for (int i = 0; i < 4; ++i) {
#pragma unroll
      for (int j = 0; j < 4; ++j)
        acc[i][j] =
            __builtin_amdgcn_mfma_i32_16x16x64_i8(af[i], bf[j], acc[i][j], 0, 0, 0);
    }
  }

  float amax = __uint_as_float(*amax_bits);
  float s = amax / 127.0f;
  if (s == 0.0f) s = 1.0f;
  const float cs = s * wscale[0];

  // C/D layout (dtype-independent, verified): col = lane&15, row = quad*4+reg
#pragma unroll
  for (int i = 0; i < 4; ++i) {
#pragma unroll
    for (int j = 0; j < 4; ++j) {
      const int n = bN + wcol * 64 + j * 16 + l16;
#pragma unroll
      for (int r = 0; r < 4; ++r) {
        const int m = bM + wrow * 64 + i * 16 + quad * 4 + r;
        C[(size_t)m * N + n] = (float)acc[i][j][r] * cs + bias[n];
      }
    }
  }
}

extern "C" void kernel_launch(void* const* d_in, const int* in_sizes, int n_in,
                              void* d_out, int out_size, void* d_ws,
                              size_t ws_size, hipStream_t stream) {
  const float* x = (const float*)d_in[0];
  const int* qw = (const int*)d_in[1];
  const float* wscale = (const float*)d_in[2];
  const float* bias = (const float*)d_in[3];
  float* out = (float*)d_out;

  const int nx = in_sizes[0];       // B*S*I = 33,554,432
  const int npacked = in_sizes[1];  // O * I/2 = 8,388,608
  const int O = in_sizes[3];        // 4096
  const int I = (npacked / O) * 2;  // 4096
  const int M = nx / I;             // 8192

  unsigned* amax = (unsigned*)d_ws;
  char* qx = (char*)d_ws + 256;
  char* w8 = qx + (size_t)nx;

  hipMemsetAsync(d_ws, 0, 4, stream);  // amax := 0 (ws is poisoned 0xAA)
  amax_kernel<<<2048, 256, 0, stream>>>(x, amax, nx / 4);
  quant_kernel<<<2048, 256, 0, stream>>>(x, amax, (unsigned*)qx, nx / 4);
  repack_kernel<<<1024, 256, 0, stream>>>(qw, (uint2*)w8, npacked / 4);

  dim3 grid(M / BM, O / BN);
  gemm_i8<<<grid, 256, 0, stream>>>(qx, w8, bias, amax, wscale, out, M, O, I);
}